// Round 2
// baseline (931.130 us; speedup 1.0000x reference)
//
#include <hip/hip_runtime.h>
#include <hip/hip_bf16.h>

typedef unsigned short u16;
typedef __bf16 bf16x8 __attribute__((ext_vector_type(8)));
typedef float f32x4 __attribute__((ext_vector_type(4)));

#define E_ 8
#define H_ 2048
#define D_ 2048
#define T_ 2048
#define N2_ 4096

__device__ __forceinline__ u16 f2bf(float f) {
    unsigned u = __builtin_bit_cast(unsigned, f);
    unsigned r = (u + 0x7FFFu + ((u >> 16) & 1u)) >> 16;
    return (u16)r;
}

typedef __attribute__((address_space(1))) const void* gptr_t;
typedef __attribute__((address_space(3))) void* lptr_t;
__device__ __forceinline__ void gload16(const void* g, void* l) {
    // async global->LDS, 16B/lane; LDS dest = wave-uniform base + lane*16
    __builtin_amdgcn_global_load_lds((gptr_t)g, (lptr_t)l, 16, 0, 0);
}

// ---------------- conversion / transpose pre-pass ----------------

__global__ __launch_bounds__(256) void k_convert_x(const float4* __restrict__ x,
                                                   ushort4* __restrict__ xb) {
    int i = blockIdx.x * 256 + threadIdx.x;   // exactly T_*H_/4 threads
    float4 v = x[i];
    ushort4 o;
    o.x = f2bf(v.x); o.y = f2bf(v.y); o.z = f2bf(v.z); o.w = f2bf(v.w);
    xb[i] = o;
}

// gate_up_w fp32 [E][H][2D] -> wP bf16 [E][4096][H]: transpose + de-interleave
// into 16-col gate/up groups:  gate d -> row ((d>>4)<<5)+(d&15),
//                              up   d -> row ((d>>4)<<5)+16+(d&15).
// GEMM1 is then a single-B GEMM whose output n-frags alternate gate/up every
// 16 columns -> GLU pairing is in-register (acc[i][2m]/acc[i][2m+1]).
__global__ __launch_bounds__(256) void k_tr_gateup(const float* __restrict__ w,
                                                   u16* __restrict__ wP) {
    __shared__ u16 Gs[64 * 73];
    __shared__ u16 Us[64 * 73];
    const int e = blockIdx.z, h0 = blockIdx.x * 64, d0 = blockIdx.y * 64;
    const int tid = threadIdx.x;
    {
        const int hl = tid >> 2;               // 0..63
        const int cseg = (tid & 3) * 32;       // fp32 col offset within 128
        const float* src = w + ((size_t)e * H_ + h0 + hl) * N2_ + 2 * d0 + cseg;
#pragma unroll
        for (int q = 0; q < 8; q++) {
            float4 v = *(const float4*)(src + q * 4);
            int dl = (cseg + q * 4) >> 1;      // even
            Gs[hl * 73 + dl]     = f2bf(v.x);
            Us[hl * 73 + dl]     = f2bf(v.y);
            Gs[hl * 73 + dl + 1] = f2bf(v.z);
            Us[hl * 73 + dl + 1] = f2bf(v.w);
        }
    }
    __syncthreads();
    {
        const int dl = tid >> 2;
        const int hseg = (tid & 3) * 16;
        u16 vg[16] __attribute__((aligned(16)));
        u16 vu[16] __attribute__((aligned(16)));
#pragma unroll
        for (int j = 0; j < 16; j++) {
            vg[j] = Gs[(hseg + j) * 73 + dl];
            vu[j] = Us[(hseg + j) * 73 + dl];
        }
        const int d = d0 + dl;
        const int rg = ((d >> 4) << 5) + (d & 15);
        size_t obg = ((size_t)e * N2_ + rg) * H_ + h0 + hseg;
        size_t obu = obg + (size_t)16 * H_;
        *(uint4*)&wP[obg]     = *(const uint4*)&vg[0];
        *(uint4*)&wP[obg + 8] = *(const uint4*)&vg[8];
        *(uint4*)&wP[obu]     = *(const uint4*)&vu[0];
        *(uint4*)&wP[obu + 8] = *(const uint4*)&vu[8];
    }
}

// down_w fp32 [E][D][H] -> wdT bf16 [E][H][D]  (transpose)
__global__ __launch_bounds__(256) void k_tr_down(const float* __restrict__ w,
                                                 u16* __restrict__ wdT) {
    __shared__ u16 Ts[64 * 73];
    const int e = blockIdx.z, d0 = blockIdx.x * 64, h0 = blockIdx.y * 64;
    const int tid = threadIdx.x;
    {
        const int dl = tid >> 2;
        const int hseg = (tid & 3) * 16;
        const float* src = w + ((size_t)e * D_ + d0 + dl) * H_ + h0 + hseg;
#pragma unroll
        for (int q = 0; q < 4; q++) {
            float4 v = *(const float4*)(src + q * 4);
            int hl = hseg + q * 4;
            Ts[(hl + 0) * 73 + dl] = f2bf(v.x);
            Ts[(hl + 1) * 73 + dl] = f2bf(v.y);
            Ts[(hl + 2) * 73 + dl] = f2bf(v.z);
            Ts[(hl + 3) * 73 + dl] = f2bf(v.w);
        }
    }
    __syncthreads();
    {
        const int hl = tid >> 2;
        const int dseg = (tid & 3) * 16;
        u16 vd[16] __attribute__((aligned(16)));
#pragma unroll
        for (int j = 0; j < 16; j++) vd[j] = Ts[hl * 73 + dseg + j];
        size_t ob = ((size_t)e * H_ + h0 + hl) * D_ + d0 + dseg;
        *(uint4*)&wdT[ob]     = *(const uint4*)&vd[0];
        *(uint4*)&wdT[ob + 8] = *(const uint4*)&vd[8];
    }
}

// ---------------- 256x256 / BK=64 / 8-wave / 8-phase GEMM machinery --------
//
// R1 rework: balanced 8/4/8/4 ds_reads per phase (was 12/4/8/0), quadrant
// order (0,0),(0,1),(1,1),(1,0), B-frags ping-ponged between exactly TWO
// register sets bfP/bfQ (max-live = 2 sets -> same VGPR count as before):
//   ph1: [rd af<-As0.m0 |st As1.h0<-A(ka)] Q(0,0)bfP
//   ph2: [rd bfQ<-Bs0.n1|st As1.h1       ] Q(0,1)bfQ
//   ph3: [rd af<-As0.m1 |st Bs0.h0<-B(kb)] Q(1,1)bfQ  vmcnt(6)
//   ph4: [rd bfQ<-Bs1.n0|st Bs0.h1       ] Q(1,0)bfP  vmcnt(4)
//   ph5: [rd af<-As1.m0 |st As0.h0<-A(kb)] Q(0,0)bfQ
//   ph6: [rd bfP<-Bs1.n1|st As0.h1       ] Q(0,1)bfP
//   ph7: [rd af<-As1.m1 |st Bs1.h0<-B(kc)] Q(1,1)bfP  vmcnt(6)
//   ph8: [rd bfP<-Bs0.n0|st Bs1.h1       ] Q(1,0)bfQ  vmcnt(4)
// vmcnt cover (each wait = half-tiles issued 4-6 phases prior, never 0):
//   ph3 w6 -> drains prev ph7,8 (Bs1=B(T1))   needed by ph4/ph6 reads
//   ph4 w4 -> drains ph1,2 (As1=A(T1))        needed by ph5/ph7 reads
//   ph7 w6 -> drains ph3,4 (Bs0=B(T2))        needed by ph8/next-ph2 reads
//   ph8 w4 -> drains ph5,6 (As0=A(T2))        needed by next-ph1/ph3 reads
// sched_barrier(0) after each lgkmcnt(0) pins the MFMA cluster (rule #18).

#define UNROLL _Pragma("unroll")
#define FRAG(bufp, r, fc) (*(const bf16x8*)&(bufp)[(r) * 64 + ((((fc) ^ ((r) & 7))) << 3)])

#define LOAD_A(Ac, mh)                                                        \
    UNROLL for (int i4 = 0; i4 < 4; i4++)                                     \
    UNROLL for (int kk = 0; kk < 2; kk++)                                     \
        af[i4][kk] = FRAG(Ac, wr + (mh) * 64 + i4 * 16 + l16, kk * 4 + quad);

#define LOAD_BSET(Bc, nh, dst)                                                \
    UNROLL for (int j2 = 0; j2 < 2; j2++)                                     \
    UNROLL for (int kk = 0; kk < 2; kk++)                                     \
        dst[j2][kk] = FRAG(Bc, wc + (nh) * 32 + j2 * 16 + l16, kk * 4 + quad);

#define MFMA_Q(mh, nh, bset)                                                  \
    __builtin_amdgcn_s_barrier();                                             \
    asm volatile("s_waitcnt lgkmcnt(0)" ::: "memory");                        \
    __builtin_amdgcn_sched_barrier(0);                                        \
    __builtin_amdgcn_s_setprio(1);                                            \
    UNROLL for (int i4 = 0; i4 < 4; i4++)                                     \
    UNROLL for (int j2 = 0; j2 < 2; j2++)                                     \
    UNROLL for (int kk = 0; kk < 2; kk++)                                     \
        acc[(mh) * 4 + i4][(nh) * 2 + j2] = __builtin_amdgcn_mfma_f32_16x16x32_bf16( \
            af[i4][kk], bset[j2][kk], acc[(mh) * 4 + i4][(nh) * 2 + j2], 0, 0, 0);   \
    __builtin_amdgcn_s_setprio(0);

#define VMW6 asm volatile("s_waitcnt vmcnt(6)" ::: "memory");
#define VMW4 asm volatile("s_waitcnt vmcnt(4)" ::: "memory");
#define BAR __builtin_amdgcn_s_barrier();

// stage one 128-row half-tile into lb; 2 gload16/lane (= 2 vmcnt events)
__device__ __forceinline__ void stage128(const u16* gp, size_t ldg, u16* lb,
                                         int wave, int sr, int csrc) {
    gload16(gp + (size_t)(wave * 8 + sr) * ldg + csrc, lb + wave * 8 * 64);
    gload16(gp + (size_t)(wave * 8 + sr + 64) * ldg + csrc, lb + (wave * 8 + 64) * 64);
}

// prologue: buf0.A, buf0.B, buf1.B in flight; drain A0/B0, keep B1 in flight
#define KPRO8(APTRX, BPTRX, LDG)                                              \
    stage128(APTRX(0), LDG, As0, wave, sr, csrc);                             \
    stage128(APTRX(0) + (size_t)128 * (LDG), LDG, As0 + 128 * 64, wave, sr, csrc); \
    stage128(BPTRX(0), LDG, Bs0, wave, sr, csrc);                             \
    stage128(BPTRX(0) + (size_t)128 * (LDG), LDG, Bs0 + 128 * 64, wave, sr, csrc); \
    stage128(BPTRX(1), LDG, Bs1, wave, sr, csrc);                             \
    stage128(BPTRX(1) + (size_t)128 * (LDG), LDG, Bs1 + 128 * 64, wave, sr, csrc); \
    VMW4; BAR;                                                                \
    LOAD_BSET(Bs0, 0, bfP);

#define KLOOP8(APTRX, BPTRX, LDG, NTK)                                        \
    for (int it = 0; it < (NTK) / 2; ++it) {                                  \
        const int ka = 2 * it + 1;                                            \
        const int kb = (2 * it + 2 < (NTK)) ? 2 * it + 2 : (NTK)-1;           \
        const int kc = (2 * it + 3 < (NTK)) ? 2 * it + 3 : (NTK)-1;           \
        LOAD_A(As0, 0);                                                       \
        stage128(APTRX(ka), LDG, As1, wave, sr, csrc);                        \
        MFMA_Q(0, 0, bfP); BAR;                                               \
        LOAD_BSET(Bs0, 1, bfQ);                                               \
        stage128(APTRX(ka) + (size_t)128 * (LDG), LDG, As1 + 128 * 64, wave, sr, csrc); \
        MFMA_Q(0, 1, bfQ); BAR;                                               \
        LOAD_A(As0, 1);                                                       \
        stage128(BPTRX(kb), LDG, Bs0, wave, sr, csrc);                        \
        MFMA_Q(1, 1, bfQ); VMW6; BAR;                                         \
        LOAD_BSET(Bs1, 0, bfQ);                                               \
        stage128(BPTRX(kb) + (size_t)128 * (LDG), LDG, Bs0 + 128 * 64, wave, sr, csrc); \
        MFMA_Q(1, 0, bfP); VMW4; BAR;                                         \
        LOAD_A(As1, 0);                                                       \
        stage128(APTRX(kb), LDG, As0, wave, sr, csrc);                        \
        MFMA_Q(0, 0, bfQ); BAR;                                               \
        LOAD_BSET(Bs1, 1, bfP);                                               \
        stage128(APTRX(kb) + (size_t)128 * (LDG), LDG, As0 + 128 * 64, wave, sr, csrc); \
        MFMA_Q(0, 1, bfP); BAR;                                               \
        LOAD_A(As1, 1);                                                       \
        stage128(BPTRX(kc), LDG, Bs1, wave, sr, csrc);                        \
        MFMA_Q(1, 1, bfP); VMW6; BAR;                                         \
        LOAD_BSET(Bs0, 0, bfP);                                               \
        stage128(BPTRX(kc) + (size_t)128 * (LDG), LDG, Bs1 + 128 * 64, wave, sr, csrc); \
        MFMA_Q(1, 0, bfQ); VMW4; BAR;                                         \
    }

// ---------------- GEMM 1: gate_up + GLU epilogue (rw folded in) ----------------

__global__ __launch_bounds__(512, 2) void k_gemm_gateup(
    const u16* __restrict__ xb,    // [T][H] bf16
    const u16* __restrict__ wP,    // [E][4096][H] bf16, gate/up 16-col groups
    const float* __restrict__ gub, // [E][2D] fp32 interleaved
    const float* __restrict__ rw,  // [T][E] fp32
    u16* __restrict__ fused)       // [E][T][D] bf16
{
    // grid 1024; XCD k owns n-tiles {2k,2k+1} for all e; t fastest on-XCD.
    const int id = blockIdx.x;
    const int xcd = id & 7;
    const int local = id >> 3;            // 0..127
    const int e = local >> 4;
    const int rem = local & 15;
    const int t0 = (rem & 7) * 256;
    const int n0 = (xcd * 2 + (rem >> 3)) * 256;

    __shared__ u16 As[2 * 256 * 64];
    __shared__ u16 Bs[2 * 256 * 64];
    u16* As0 = As;  u16* As1 = As + 256 * 64;
    u16* Bs0 = Bs;  u16* Bs1 = Bs + 256 * 64;

    const int tid = threadIdx.x;
    const int lane = tid & 63;
    const int wave = tid >> 6;
    const int wr = (wave >> 2) * 128;
    const int wc = (wave & 3) * 64;
    const int l16 = lane & 15;
    const int quad = lane >> 4;
    const int sr = lane >> 3;
    const int csrc = ((lane & 7) ^ sr) * 8;

    const u16* Ab = xb + (size_t)t0 * H_;
    const u16* Bb = wP + ((size_t)e * N2_ + n0) * H_;
#define APTR1(kt) (Ab + (kt) * 64)
#define BPTR1(kt) (Bb + (kt) * 64)

    f32x4 acc[8][4];
    const f32x4 vzero = {0.f, 0.f, 0.f, 0.f};
    UNROLL for (int i = 0; i < 8; i++)
        UNROLL for (int j = 0; j < 4; j++) acc[i][j] = vzero;
    bf16x8 af[4][2], bfP[2][2], bfQ[2][2];

    KPRO8(APTR1, BPTR1, H_)
    KLOOP8(APTR1, BPTR1, H_, (H_ / 64))
#undef APTR1
#undef BPTR1

    // epilogue: n-frag pair (2m, 2m+1) = (gate, up) for the same d
    const float* gbe = gub + e * N2_;
    const int dbase = (n0 + wc) >> 1;
    u16* fbase = fused + (size_t)e * T_ * D_;
    UNROLL for (int i = 0; i < 8; i++) {
        UNROLL for (int m = 0; m < 2; m++) {
            const int d = dbase + m * 16 + l16;
            const float bg = gbe[2 * d];
            const float bu = gbe[2 * d + 1];
            UNROLL for (int r = 0; r < 4; r++) {
                const int row = t0 + wr + i * 16 + quad * 4 + r;
                float g = acc[i][2 * m][r] + bg;
                float u = acc[i][2 * m + 1][r] + bu;
                g = fminf(g, 7.0f);
                u = fminf(fmaxf(u, -7.0f), 7.0f);
                float glu = g / (1.0f + __expf(-1.702f * g));
                float f = (u + 1.0f) * glu * rw[row * E_ + e];
                fbase[(size_t)row * D_ + d] = f2bf(f);
            }
        }
    }
}

// ---------------- GEMM 2: down proj, experts-in-K (K=4096), 256x256 --------

__global__ __launch_bounds__(512, 2) void k_gemm_down(
    const u16* __restrict__ fused, // [E][T][D] bf16 (rw-scaled)
    const u16* __restrict__ wdT,   // [E][H][D] bf16
    float* __restrict__ pout)      // [4][T][H] fp32 partials
{
    // grid 256 = exactly 1 block/CU; XCD k owns h-tile k; t fastest.
    const int id = blockIdx.x;
    const int xcd = id & 7;
    const int local = id >> 3;           // 0..31
    const int g = local >> 3;            // expert pair
    const int t0 = (local & 7) * 256;
    const int h0 = xcd * 256;
    const int e0 = g * 2;

    __shared__ u16 As[2 * 256 * 64];
    __shared__ u16 Bs[2 * 256 * 64];
    u16* As0 = As;  u16* As1 = As + 256 * 64;
    u16* Bs0 = Bs;  u16* Bs1 = Bs + 256 * 64;

    const int tid = threadIdx.x;
    const int lane = tid & 63;
    const int wave = tid >> 6;
    const int wr = (wave >> 2) * 128;
    const int wc = (wave & 3) * 64;
    const int l16 = lane & 15;
    const int quad = lane >> 4;
    const int sr = lane >> 3;
    const int csrc = ((lane & 7) ^ sr) * 8;

#define APTR2(kt) (fused + ((size_t)(e0 + ((kt) >> 5)) * T_ + t0) * D_ + ((kt) & 31) * 64)
#define BPTR2(kt) (wdT + ((size_t)(e0 + ((kt) >> 5)) * H_ + h0) * D_ + ((kt) & 31) * 64)

    f32x4 acc[8][4];
    const f32x4 vzero = {0.f, 0.f, 0.f, 0.f};
    UNROLL for (int i = 0; i < 8; i++)
        UNROLL for (int j = 0; j < 4; j++) acc[i][j] = vzero;
    bf16x8 af[4][2], bfP[2][2], bfQ[2][2];

    KPRO8(APTR2, BPTR2, D_)
    KLOOP8(APTR2, BPTR2, D_, (2 * (D_ / 64)))
#undef APTR2
#undef BPTR2

    float* po = pout + (size_t)g * T_ * H_;
    UNROLL for (int i = 0; i < 8; i++) {
        UNROLL for (int r = 0; r < 4; r++) {
            const int row = t0 + wr + i * 16 + quad * 4 + r;
            UNROLL for (int j = 0; j < 4; j++) {
                po[(size_t)row * H_ + h0 + wc + j * 16 + l16] = acc[i][j][r];
            }
        }
    }
}

// out[t][h] = sum_g pout[g] + sum_e rw[t][e] * down_b[e][h]   (float4)
__global__ __launch_bounds__(256) void k_combine(const float4* __restrict__ p,
                                                 const float* __restrict__ rw,
                                                 const float4* __restrict__ db,
                                                 float4* __restrict__ out) {
    int i = blockIdx.x * 256 + threadIdx.x;   // T_*H_/4 elements
    int t = i >> 9;                            // H_/4 = 512 float4 per row
    int h4 = i & 511;
    const size_t TH4 = (size_t)T_ * H_ / 4;
    float4 s0 = p[i], s1 = p[i + TH4], s2 = p[i + 2 * TH4], s3 = p[i + 3 * TH4];
    float4 a;
    a.x = s0.x + s1.x + s2.x + s3.x;
    a.y = s0.y + s1.y + s2.y + s3.y;
    a.z = s0.z + s1.z + s2.z + s3.z;
    a.w = s0.w + s1.w + s2.w + s3.w;
#pragma unroll
    for (int e = 0; e < E_; e++) {
        float w = rw[t * E_ + e];
        float4 b = db[e * (H_ / 4) + h4];
        a.x += w * b.x; a.y += w * b.y; a.z += w * b.z; a.w += w * b.w;
    }
    out[i] = a;
}

// ---------------- launch ----------------

extern "C" void kernel_launch(void* const* d_in, const int* in_sizes, int n_in,
                              void* d_out, int out_size, void* d_ws, size_t ws_size,
                              hipStream_t stream) {
    const float* x   = (const float*)d_in[0];   // [B,S,H]
    const float* rw  = (const float*)d_in[1];   // [T,E]
    const float* guw = (const float*)d_in[2];   // [E,H,2D]
    const float* gub = (const float*)d_in[3];   // [E,2D]
    const float* dww = (const float*)d_in[4];   // [E,D,H]
    const float* dwb = (const float*)d_in[5];   // [E,H]
    float* out = (float*)d_out;

    char* ws = (char*)d_ws;
    u16* xb    = (u16*)(ws);                      //   8 MB  [T][H]
    u16* wP    = (u16*)(ws + 8388608);            // 128 MB  [E][4096][H]
    u16* wdT   = (u16*)(ws + 142606336);          //  64 MB  [E][H][D]
    u16* fused = (u16*)(ws + 209715200);          //  64 MB  [E][T][D]
    // pout (64 MB fp32 [4][T][H]) reuses the wP region — dead after gemm1.
    float* pout = (float*)(ws + 8388608);

    k_convert_x<<<dim3((T_ * H_) / 4 / 256), 256, 0, stream>>>((const float4*)x, (ushort4*)xb);
    k_tr_gateup<<<dim3(H_ / 64, D_ / 64, E_), 256, 0, stream>>>(guw, wP);
    k_tr_down<<<dim3(D_ / 64, H_ / 64, E_), 256, 0, stream>>>(dww, wdT);
    k_gemm_gateup<<<dim3(1024), 512, 0, stream>>>(xb, wP, gub, rw, fused);
    k_gemm_down<<<dim3(256), 512, 0, stream>>>(fused, wdT, pout);
    k_combine<<<dim3((T_ * H_) / 4 / 256), 256, 0, stream>>>((const float4*)pout, rw, (const float4*)dwb, (float4*)out);
}

// Round 4
// 825.229 us; speedup vs baseline: 1.1283x; 1.1283x over previous
//
#include <hip/hip_runtime.h>
#include <hip/hip_bf16.h>

typedef unsigned short u16;
typedef __bf16 bf16x8 __attribute__((ext_vector_type(8)));
typedef float f32x4 __attribute__((ext_vector_type(4)));

#define E_ 8
#define H_ 2048
#define D_ 2048
#define T_ 2048
#define N2_ 4096

__device__ __forceinline__ u16 f2bf(float f) {
    unsigned u = __builtin_bit_cast(unsigned, f);
    unsigned r = (u + 0x7FFFu + ((u >> 16) & 1u)) >> 16;
    return (u16)r;
}

typedef __attribute__((address_space(1))) const void* gptr_t;
typedef __attribute__((address_space(3))) void* lptr_t;
__device__ __forceinline__ void gload16(const void* g, void* l) {
    // async global->LDS, 16B/lane; LDS dest = wave-uniform base + lane*16
    __builtin_amdgcn_global_load_lds((gptr_t)g, (lptr_t)l, 16, 0, 0);
}
__device__ __forceinline__ unsigned lds_addr(void* p) {
    return (unsigned)(size_t)(lptr_t)p;   // 32-bit LDS byte offset
}

// ---------------- conversion / transpose pre-pass ----------------

__global__ __launch_bounds__(256) void k_convert_x(const float4* __restrict__ x,
                                                   ushort4* __restrict__ xb) {
    int i = blockIdx.x * 256 + threadIdx.x;   // exactly T_*H_/4 threads
    float4 v = x[i];
    ushort4 o;
    o.x = f2bf(v.x); o.y = f2bf(v.y); o.z = f2bf(v.z); o.w = f2bf(v.w);
    xb[i] = o;
}

// gate_up_w fp32 [E][H][2D] -> wP bf16 [E][4096][H]: transpose + de-interleave
// into 16-col gate/up groups:  gate d -> row ((d>>4)<<5)+(d&15),
//                              up   d -> row ((d>>4)<<5)+16+(d&15).
__global__ __launch_bounds__(256) void k_tr_gateup(const float* __restrict__ w,
                                                   u16* __restrict__ wP) {
    __shared__ u16 Gs[64 * 73];
    __shared__ u16 Us[64 * 73];
    const int e = blockIdx.z, h0 = blockIdx.x * 64, d0 = blockIdx.y * 64;
    const int tid = threadIdx.x;
    {
        const int hl = tid >> 2;               // 0..63
        const int cseg = (tid & 3) * 32;       // fp32 col offset within 128
        const float* src = w + ((size_t)e * H_ + h0 + hl) * N2_ + 2 * d0 + cseg;
#pragma unroll
        for (int q = 0; q < 8; q++) {
            float4 v = *(const float4*)(src + q * 4);
            int dl = (cseg + q * 4) >> 1;      // even
            Gs[hl * 73 + dl]     = f2bf(v.x);
            Us[hl * 73 + dl]     = f2bf(v.y);
            Gs[hl * 73 + dl + 1] = f2bf(v.z);
            Us[hl * 73 + dl + 1] = f2bf(v.w);
        }
    }
    __syncthreads();
    {
        const int dl = tid >> 2;
        const int hseg = (tid & 3) * 16;
        u16 vg[16] __attribute__((aligned(16)));
        u16 vu[16] __attribute__((aligned(16)));
#pragma unroll
        for (int j = 0; j < 16; j++) {
            vg[j] = Gs[(hseg + j) * 73 + dl];
            vu[j] = Us[(hseg + j) * 73 + dl];
        }
        const int d = d0 + dl;
        const int rg = ((d >> 4) << 5) + (d & 15);
        size_t obg = ((size_t)e * N2_ + rg) * H_ + h0 + hseg;
        size_t obu = obg + (size_t)16 * H_;
        *(uint4*)&wP[obg]     = *(const uint4*)&vg[0];
        *(uint4*)&wP[obg + 8] = *(const uint4*)&vg[8];
        *(uint4*)&wP[obu]     = *(const uint4*)&vu[0];
        *(uint4*)&wP[obu + 8] = *(const uint4*)&vu[8];
    }
}

// down_w fp32 [E][D][H] -> wdT bf16 [E][H][D]  (transpose)
__global__ __launch_bounds__(256) void k_tr_down(const float* __restrict__ w,
                                                 u16* __restrict__ wdT) {
    __shared__ u16 Ts[64 * 73];
    const int e = blockIdx.z, d0 = blockIdx.x * 64, h0 = blockIdx.y * 64;
    const int tid = threadIdx.x;
    {
        const int dl = tid >> 2;
        const int hseg = (tid & 3) * 16;
        const float* src = w + ((size_t)e * D_ + d0 + dl) * H_ + h0 + hseg;
#pragma unroll
        for (int q = 0; q < 4; q++) {
            float4 v = *(const float4*)(src + q * 4);
            int hl = hseg + q * 4;
            Ts[(hl + 0) * 73 + dl] = f2bf(v.x);
            Ts[(hl + 1) * 73 + dl] = f2bf(v.y);
            Ts[(hl + 2) * 73 + dl] = f2bf(v.z);
            Ts[(hl + 3) * 73 + dl] = f2bf(v.w);
        }
    }
    __syncthreads();
    {
        const int hl = tid >> 2;
        const int dseg = (tid & 3) * 16;
        u16 vd[16] __attribute__((aligned(16)));
#pragma unroll
        for (int j = 0; j < 16; j++) vd[j] = Ts[hl * 73 + dseg + j];
        size_t ob = ((size_t)e * H_ + h0 + hl) * D_ + d0 + dseg;
        *(uint4*)&wdT[ob]     = *(const uint4*)&vd[0];
        *(uint4*)&wdT[ob + 8] = *(const uint4*)&vd[8];
    }
}

// ---------------- 256x256 / BK=64 / 8-wave / 8-phase GEMM machinery --------
//
// R3: fragment ds_reads are inline-asm ds_read_b128 with 4 precomputed
// per-lane address VGPRs (la0,la1 = A kk0/kk1; lb0,lb1 = B kk0/kk1) and
// compile-time immediates encoding {buffer(+32768), mh*8192|nh*4096,
// i4*2048|j2*2048}. The swizzle XOR folds into the base (r&7 == l16&7 for
// all fragment rows). Zero per-read VALU; sched_barrier(0) after lgkmcnt(0)
// pins the cluster (rule #18). MFMA cluster is kk-outer (dependent pairs 8
// issues apart). Schedule/vmcnt discipline identical to R2 (cover verified):
//   ph1 LDA(b0,m0)           st As1.h0(ka)  Q(0,0)bfP
//   ph2 LDB(b0,n1)->bfQ      st As1.h1      Q(0,1)bfQ
//   ph3 LDA(b0,m1)           st Bs0.h0(kb)  Q(1,1)bfQ  vmcnt(6)
//   ph4 LDB(b1,n0)->bfQ      st Bs0.h1      Q(1,0)bfP  vmcnt(4)
//   ph5 LDA(b1,m0)           st As0.h0(kb)  Q(0,0)bfQ
//   ph6 LDB(b1,n1)->bfP      st As0.h1      Q(0,1)bfP
//   ph7 LDA(b1,m1)           st Bs1.h0(kc)  Q(1,1)bfP  vmcnt(6)
//   ph8 LDB(b0,n0)->bfP      st Bs1.h1      Q(1,0)bfQ  vmcnt(4)

#define UNROLL _Pragma("unroll")

#define DSR(dst, vaddr, imm)                                                  \
    asm volatile("ds_read_b128 %0, %1 offset:%2"                              \
                 : "=v"(dst) : "v"(vaddr), "i"(imm));

#define LDA(BUFI, mh)                                                         \
    DSR(af[0][0], la0, (BUFI)*32768 + (mh)*8192 + 0)                          \
    DSR(af[0][1], la1, (BUFI)*32768 + (mh)*8192 + 0)                          \
    DSR(af[1][0], la0, (BUFI)*32768 + (mh)*8192 + 2048)                       \
    DSR(af[1][1], la1, (BUFI)*32768 + (mh)*8192 + 2048)                       \
    DSR(af[2][0], la0, (BUFI)*32768 + (mh)*8192 + 4096)                       \
    DSR(af[2][1], la1, (BUFI)*32768 + (mh)*8192 + 4096)                       \
    DSR(af[3][0], la0, (BUFI)*32768 + (mh)*8192 + 6144)                       \
    DSR(af[3][1], la1, (BUFI)*32768 + (mh)*8192 + 6144)

#define LDB(BUFI, nh, dst)                                                    \
    DSR(dst[0][0], lb0, (BUFI)*32768 + (nh)*4096 + 0)                         \
    DSR(dst[0][1], lb1, (BUFI)*32768 + (nh)*4096 + 0)                         \
    DSR(dst[1][0], lb0, (BUFI)*32768 + (nh)*4096 + 2048)                      \
    DSR(dst[1][1], lb1, (BUFI)*32768 + (nh)*4096 + 2048)

#define MFMA_Q(mh, nh, bset)                                                  \
    __builtin_amdgcn_s_barrier();                                             \
    asm volatile("s_waitcnt lgkmcnt(0)" ::: "memory");                        \
    __builtin_amdgcn_sched_barrier(0);                                        \
    __builtin_amdgcn_s_setprio(1);                                            \
    UNROLL for (int kk = 0; kk < 2; kk++)                                     \
    UNROLL for (int i4 = 0; i4 < 4; i4++)                                     \
    UNROLL for (int j2 = 0; j2 < 2; j2++)                                     \
        acc[(mh) * 4 + i4][(nh) * 2 + j2] = __builtin_amdgcn_mfma_f32_16x16x32_bf16( \
            af[i4][kk], bset[j2][kk], acc[(mh) * 4 + i4][(nh) * 2 + j2], 0, 0, 0);   \
    __builtin_amdgcn_s_setprio(0);

#define VMW6 asm volatile("s_waitcnt vmcnt(6)" ::: "memory");
#define VMW4 asm volatile("s_waitcnt vmcnt(4)" ::: "memory");
#define BAR __builtin_amdgcn_s_barrier();

// stage one 128-row half-tile into lb; 2 gload16/lane (= 2 vmcnt events)
__device__ __forceinline__ void stage128(const u16* gp, size_t ldg, u16* lb,
                                         int wave, int sr, int csrc) {
    gload16(gp + (size_t)(wave * 8 + sr) * ldg + csrc, lb + wave * 8 * 64);
    gload16(gp + (size_t)(wave * 8 + sr + 64) * ldg + csrc, lb + (wave * 8 + 64) * 64);
}

// prologue: stage A0,B0 (kt0) + B1 (kt1); drain A0/B0, keep B1 in flight
#define KPRO8(APTRX, BPTRX, LDG)                                              \
    stage128(APTRX(0), LDG, As0, wave, sr, csrc);                             \
    stage128(APTRX(0) + (size_t)128 * (LDG), LDG, As0 + 128 * 64, wave, sr, csrc); \
    stage128(BPTRX(0), LDG, Bs0, wave, sr, csrc);                             \
    stage128(BPTRX(0) + (size_t)128 * (LDG), LDG, Bs0 + 128 * 64, wave, sr, csrc); \
    stage128(BPTRX(1), LDG, Bs1, wave, sr, csrc);                             \
    stage128(BPTRX(1) + (size_t)128 * (LDG), LDG, Bs1 + 128 * 64, wave, sr, csrc); \
    VMW4; BAR;                                                                \
    LDB(0, 0, bfP)

#define KLOOP8(APTRX, BPTRX, LDG, NTK)                                        \
    for (int it = 0; it < (NTK) / 2; ++it) {                                  \
        const int ka = 2 * it + 1;                                            \
        const int kb = (2 * it + 2 < (NTK)) ? 2 * it + 2 : (NTK)-1;           \
        const int kc = (2 * it + 3 < (NTK)) ? 2 * it + 3 : (NTK)-1;           \
        LDA(0, 0)                                                             \
        stage128(APTRX(ka), LDG, As1, wave, sr, csrc);                        \
        MFMA_Q(0, 0, bfP) BAR;                                                \
        LDB(0, 1, bfQ)                                                        \
        stage128(APTRX(ka) + (size_t)128 * (LDG), LDG, As1 + 128 * 64, wave, sr, csrc); \
        MFMA_Q(0, 1, bfQ) BAR;                                                \
        LDA(0, 1)                                                             \
        stage128(BPTRX(kb), LDG, Bs0, wave, sr, csrc);                        \
        MFMA_Q(1, 1, bfQ) VMW6; BAR;                                          \
        LDB(1, 0, bfQ)                                                        \
        stage128(BPTRX(kb) + (size_t)128 * (LDG), LDG, Bs0 + 128 * 64, wave, sr, csrc); \
        MFMA_Q(1, 0, bfP) VMW4; BAR;                                          \
        LDA(1, 0)                                                             \
        stage128(APTRX(kb), LDG, As0, wave, sr, csrc);                        \
        MFMA_Q(0, 0, bfQ) BAR;                                                \
        LDB(1, 1, bfP)                                                        \
        stage128(APTRX(kb) + (size_t)128 * (LDG), LDG, As0 + 128 * 64, wave, sr, csrc); \
        MFMA_Q(0, 1, bfP) BAR;                                                \
        LDA(1, 1)                                                             \
        stage128(BPTRX(kc), LDG, Bs1, wave, sr, csrc);                        \
        MFMA_Q(1, 1, bfP) VMW6; BAR;                                          \
        LDB(0, 0, bfP)                                                        \
        stage128(BPTRX(kc) + (size_t)128 * (LDG), LDG, Bs1 + 128 * 64, wave, sr, csrc); \
        MFMA_Q(1, 0, bfQ) VMW4; BAR;                                          \
    }

#define GEMM_SETUP                                                            \
    const int tid = threadIdx.x;                                              \
    const int lane = tid & 63;                                                \
    const int wave = tid >> 6;                                                \
    const int wr = (wave >> 2) * 128;                                         \
    const int wc = (wave & 3) * 64;                                           \
    const int l16 = lane & 15;                                                \
    const int quad = lane >> 4;                                               \
    const int sr = lane >> 3;                                                 \
    const int csrc = ((lane & 7) ^ sr) * 8;                                   \
    u16* As0 = As;  u16* As1 = As + 256 * 64;                                 \
    u16* Bs0 = Bs;  u16* Bs1 = Bs + 256 * 64;                                 \
    const unsigned swz0 = ((unsigned)((0 * 4 + quad) ^ (l16 & 7))) * 16;      \
    const unsigned swz1 = ((unsigned)((1 * 4 + quad) ^ (l16 & 7))) * 16;      \
    const unsigned la0 = lds_addr(As) + (unsigned)(wr + l16) * 128 + swz0;    \
    const unsigned la1 = lds_addr(As) + (unsigned)(wr + l16) * 128 + swz1;    \
    const unsigned lb0 = lds_addr(Bs) + (unsigned)(wc + l16) * 128 + swz0;    \
    const unsigned lb1 = lds_addr(Bs) + (unsigned)(wc + l16) * 128 + swz1;    \
    f32x4 acc[8][4];                                                          \
    const f32x4 vzero = {0.f, 0.f, 0.f, 0.f};                                 \
    UNROLL for (int i = 0; i < 8; i++)                                        \
        UNROLL for (int j = 0; j < 4; j++) acc[i][j] = vzero;                 \
    bf16x8 af[4][2], bfP[2][2], bfQ[2][2];

// ---------------- GEMM 1: gate_up + GLU epilogue (rw folded in) ----------------

__global__ __launch_bounds__(512, 2) void k_gemm_gateup(
    const u16* __restrict__ xb,    // [T][H] bf16
    const u16* __restrict__ wP,    // [E][4096][H] bf16, gate/up 16-col groups
    const float* __restrict__ gub, // [E][2D] fp32 interleaved
    const float* __restrict__ rw,  // [T][E] fp32
    u16* __restrict__ fused)       // [E][T][D] bf16
{
    // grid 1024; XCD k owns n-tiles {2k,2k+1} for all e; t fastest on-XCD.
    const int id = blockIdx.x;
    const int xcd = id & 7;
    const int local = id >> 3;            // 0..127
    const int e = local >> 4;
    const int rem = local & 15;
    const int t0 = (rem & 7) * 256;
    const int n0 = (xcd * 2 + (rem >> 3)) * 256;

    __shared__ u16 As[2 * 256 * 64];
    __shared__ u16 Bs[2 * 256 * 64];
    GEMM_SETUP

    const u16* Ab = xb + (size_t)t0 * H_;
    const u16* Bb = wP + ((size_t)e * N2_ + n0) * H_;
#define APTR1(kt) (Ab + (kt) * 64)
#define BPTR1(kt) (Bb + (kt) * 64)

    KPRO8(APTR1, BPTR1, H_);
    KLOOP8(APTR1, BPTR1, H_, (H_ / 64))
#undef APTR1
#undef BPTR1

    // epilogue: n-frag pair (2m, 2m+1) = (gate, up) for the same d
    const float* gbe = gub + e * N2_;
    const int dbase = (n0 + wc) >> 1;
    u16* fbase = fused + (size_t)e * T_ * D_;
    UNROLL for (int i = 0; i < 8; i++) {
        UNROLL for (int m = 0; m < 2; m++) {
            const int d = dbase + m * 16 + l16;
            const float bg = gbe[2 * d];
            const float bu = gbe[2 * d + 1];
            UNROLL for (int r = 0; r < 4; r++) {
                const int row = t0 + wr + i * 16 + quad * 4 + r;
                float g = acc[i][2 * m][r] + bg;
                float u = acc[i][2 * m + 1][r] + bu;
                g = fminf(g, 7.0f);
                u = fminf(fmaxf(u, -7.0f), 7.0f);
                float glu = g / (1.0f + __expf(-1.702f * g));
                float f = (u + 1.0f) * glu * rw[row * E_ + e];
                fbase[(size_t)row * D_ + d] = f2bf(f);
            }
        }
    }
}

// ---------------- GEMM 2: down proj, experts-in-K (K=4096), 256x256 --------

__global__ __launch_bounds__(512, 2) void k_gemm_down(
    const u16* __restrict__ fused, // [E][T][D] bf16 (rw-scaled)
    const u16* __restrict__ wdT,   // [E][H][D] bf16
    float* __restrict__ pout)      // [4][T][H] fp32 partials
{
    // grid 256 = exactly 1 block/CU; XCD k owns h-tile k; t fastest.
    const int id = blockIdx.x;
    const int xcd = id & 7;
    const int local = id >> 3;           // 0..31
    const int g = local >> 3;            // expert pair
    const int t0 = (local & 7) * 256;
    const int h0 = xcd * 256;
    const int e0 = g * 2;

    __shared__ u16 As[2 * 256 * 64];
    __shared__ u16 Bs[2 * 256 * 64];
    GEMM_SETUP

#define APTR2(kt) (fused + ((size_t)(e0 + ((kt) >> 5)) * T_ + t0) * D_ + ((kt) & 31) * 64)
#define BPTR2(kt) (wdT + ((size_t)(e0 + ((kt) >> 5)) * H_ + h0) * D_ + ((kt) & 31) * 64)

    KPRO8(APTR2, BPTR2, D_);
    KLOOP8(APTR2, BPTR2, D_, (2 * (D_ / 64)))
#undef APTR2
#undef BPTR2

    float* po = pout + (size_t)g * T_ * H_;
    UNROLL for (int i = 0; i < 8; i++) {
        UNROLL for (int r = 0; r < 4; r++) {
            const int row = t0 + wr + i * 16 + quad * 4 + r;
            UNROLL for (int j = 0; j < 4; j++) {
                po[(size_t)row * H_ + h0 + wc + j * 16 + l16] = acc[i][j][r];
            }
        }
    }
}

// out[t][h] = sum_g pout[g] + sum_e rw[t][e] * down_b[e][h]   (float4)
__global__ __launch_bounds__(256) void k_combine(const float4* __restrict__ p,
                                                 const float* __restrict__ rw,
                                                 const float4* __restrict__ db,
                                                 float4* __restrict__ out) {
    int i = blockIdx.x * 256 + threadIdx.x;   // T_*H_/4 elements
    int t = i >> 9;                            // H_/4 = 512 float4 per row
    int h4 = i & 511;
    const size_t TH4 = (size_t)T_ * H_ / 4;
    float4 s0 = p[i], s1 = p[i + TH4], s2 = p[i + 2 * TH4], s3 = p[i + 3 * TH4];
    float4 a;
    a.x = s0.x + s1.x + s2.x + s3.x;
    a.y = s0.y + s1.y + s2.y + s3.y;
    a.z = s0.z + s1.z + s2.z + s3.z;
    a.w = s0.w + s1.w + s2.w + s3.w;
#pragma unroll
    for (int e = 0; e < E_; e++) {
        float w = rw[t * E_ + e];
        float4 b = db[e * (H_ / 4) + h4];
        a.x += w * b.x; a.y += w * b.y; a.z += w * b.z; a.w += w * b.w;
    }
    out[i] = a;
}

// ---------------- launch ----------------

extern "C" void kernel_launch(void* const* d_in, const int* in_sizes, int n_in,
                              void* d_out, int out_size, void* d_ws, size_t ws_size,
                              hipStream_t stream) {
    const float* x   = (const float*)d_in[0];   // [B,S,H]
    const float* rw  = (const float*)d_in[1];   // [T,E]
    const float* guw = (const float*)d_in[2];   // [E,H,2D]
    const float* gub = (const float*)d_in[3];   // [E,2D]
    const float* dww = (const float*)d_in[4];   // [E,D,H]
    const float* dwb = (const float*)d_in[5];   // [E,H]
    float* out = (float*)d_out;

    char* ws = (char*)d_ws;
    u16* xb    = (u16*)(ws);                      //   8 MB  [T][H]
    u16* wP    = (u16*)(ws + 8388608);            // 128 MB  [E][4096][H]
    u16* wdT   = (u16*)(ws + 142606336);          //  64 MB  [E][H][D]
    u16* fused = (u16*)(ws + 209715200);          //  64 MB  [E][T][D]
    // pout (64 MB fp32 [4][T][H]) reuses the wP region — dead after gemm1.
    float* pout = (float*)(ws + 8388608);

    k_convert_x<<<dim3((T_ * H_) / 4 / 256), 256, 0, stream>>>((const float4*)x, (ushort4*)xb);
    k_tr_gateup<<<dim3(H_ / 64, D_ / 64, E_), 256, 0, stream>>>(guw, wP);
    k_tr_down<<<dim3(D_ / 64, H_ / 64, E_), 256, 0, stream>>>(dww, wdT);
    k_gemm_gateup<<<dim3(1024), 512, 0, stream>>>(xb, wP, gub, rw, fused);
    k_gemm_down<<<dim3(256), 512, 0, stream>>>(fused, wdT, pout);
    k_combine<<<dim3((T_ * H_) / 4 / 256), 256, 0, stream>>>((const float4*)pout, rw, (const float4*)dwb, (float4*)out);
}